// Round 15
// baseline (126.294 us; speedup 1.0000x reference)
//
#include <hip/hip_runtime.h>
#include <hip/hip_bf16.h>
#include <stdint.h>

#define B_ 16
#define C_ 512
#define T_ 1024
#define NH_ 8

typedef __attribute__((ext_vector_type(8))) short bf16x8;
typedef __attribute__((ext_vector_type(4))) float f32x4;
typedef __attribute__((ext_vector_type(16))) float f32x16;
typedef __attribute__((ext_vector_type(4))) unsigned short us4;
typedef __attribute__((ext_vector_type(4))) uint32_t u32x4;
typedef __attribute__((ext_vector_type(2))) uint32_t u32x2;

__device__ __forceinline__ unsigned short f2bf(float f) {
  union { float f; uint32_t u; } v; v.f = f;
  uint32_t r = v.u + 0x7FFFu + ((v.u >> 16) & 1u);
  return (unsigned short)(r >> 16);
}

__device__ __forceinline__ uint32_t cvtpk_bf16(float lo, float hi) {
  uint32_t r;
  asm("v_cvt_pk_bf16_f32 %0, %1, %2" : "=v"(r) : "v"(lo), "v"(hi));
  return r;
}

__device__ __forceinline__ f32x4 mfma_bf16(bf16x8 a, bf16x8 b, f32x4 c) {
  asm("v_mfma_f32_16x16x32_bf16 %0, %1, %2, %0" : "+v"(c) : "v"(a), "v"(b));
  return c;
}

__device__ __forceinline__ f32x16 mfma32_bf16(bf16x8 a, bf16x8 b, f32x16 c) {
  asm("v_mfma_f32_32x32x16_bf16 %0, %1, %2, %0" : "+v"(c) : "v"(a), "v"(b));
  return c;
}

// (a,b) -> a' = {a.lo32, b.lo32}, b' = {a.hi32, b.hi32}
__device__ __forceinline__ void swap32(uint32_t& a, uint32_t& b) {
  asm("v_permlane32_swap_b32 %0, %1" : "+v"(a), "+v"(b));
}

typedef const __attribute__((address_space(1))) uint32_t* gas1_t;
typedef __attribute__((address_space(3))) uint32_t* las3_t;

// async global->LDS, 16B per lane; lds dest = wave-uniform base + lane*16
__device__ __forceinline__ void async16(const void* g, void* lds) {
  __builtin_amdgcn_global_load_lds((gas1_t)(uintptr_t)g,
                                   (las3_t)(uint32_t)(uintptr_t)lds, 16, 0, 0);
}

// q pre-scale folded into QKV epilogue: scale^2 * log2(e)
#define SCLF 0.18033688011112044f

// ---------------- weight conversion fp32 -> bf16 ----------------
__global__ __launch_bounds__(256) void convert_w_kernel(
    const float* __restrict__ qkv_w, const float* __restrict__ proj_w,
    unsigned short* __restrict__ wq, unsigned short* __restrict__ wp) {
  int i = blockIdx.x * 256 + threadIdx.x;  // float4 index, 262144 total
  const float4* src;
  unsigned short* dst;
  int rel = i;
  if (i < 196608) { src = (const float4*)qkv_w; dst = wq; }
  else            { src = (const float4*)proj_w; dst = wp; rel = i - 196608; }
  float4 v = src[rel];
  us4 o;
  o.x = f2bf(v.x); o.y = f2bf(v.y); o.z = f2bf(v.z); o.w = f2bf(v.w);
  *(us4*)&dst[(size_t)rel * 4] = o;
}

// ---------------- GroupNorm, single pass, register-resident ----------------
__global__ __launch_bounds__(256) void groupnorm_kernel(
    const float* __restrict__ x, const float* __restrict__ gn_w,
    const float* __restrict__ gn_b, unsigned short* __restrict__ xnT) {
  const int blk = blockIdx.x;   // b*32+g
  const int b = blk >> 5, g = blk & 31;
  const int tid = threadIdx.x;
  const float4* x4 = (const float4*)(x + (((size_t)(b * C_ + g * 16)) << 10));

  float4 v[16];
  float s1 = 0.f, s2 = 0.f;
#pragma unroll
  for (int i = 0; i < 16; ++i) {
    v[i] = x4[tid + i * 256];
    s1 += v[i].x + v[i].y + v[i].z + v[i].w;
    s2 += v[i].x * v[i].x + v[i].y * v[i].y + v[i].z * v[i].z + v[i].w * v[i].w;
  }
#pragma unroll
  for (int m = 32; m; m >>= 1) { s1 += __shfl_xor(s1, m); s2 += __shfl_xor(s2, m); }

  __shared__ float r1[4], r2[4], stats[2];
  const int wv = tid >> 6;
  if ((tid & 63) == 0) { r1[wv] = s1; r2[wv] = s2; }
  __syncthreads();
  if (tid == 0) {
    float a = r1[0] + r1[1] + r1[2] + r1[3];
    float q = r2[0] + r2[1] + r2[2] + r2[3];
    float mean = a * (1.f / 16384.f);
    float var = q * (1.f / 16384.f) - mean * mean;
    stats[0] = mean;
    stats[1] = rsqrtf(var + 1e-5f);
  }
  __syncthreads();
  const float mean = stats[0], rsig = stats[1];

  float wc[16], bc[16];
#pragma unroll
  for (int c = 0; c < 16; ++c) {
    const float w0 = gn_w[g * 16 + c] * rsig;
    wc[c] = w0;
    bc[c] = gn_b[g * 16 + c] - mean * w0;
  }
#pragma unroll
  for (int r = 0; r < 4; ++r) {
    uint32_t o[8];
#pragma unroll
    for (int c2 = 0; c2 < 8; ++c2) {
      const float a = ((const float*)&v[2 * c2])[r] * wc[2 * c2] + bc[2 * c2];
      const float q = ((const float*)&v[2 * c2 + 1])[r] * wc[2 * c2 + 1] + bc[2 * c2 + 1];
      o[c2] = cvtpk_bf16(a, q);
    }
    unsigned short* dst = &xnT[(((size_t)(b * T_ + tid * 4 + r)) << 9) + g * 16];
    u32x4 lo; lo.x = o[0]; lo.y = o[1]; lo.z = o[2]; lo.w = o[3];
    u32x4 hi; hi.x = o[4]; hi.y = o[5]; hi.z = o[6]; hi.w = o[7];
    *(u32x4*)dst = lo;
    *(u32x4*)(dst + 8) = hi;
  }
}

// ---------------- GEMM: D[m=t][n=o] = sum_k A[t][k] * Bw[o][k] ----------------
// MODE 0: epilogue routes through LDS -> coalesced 1KB stores into 32x32-MFMA
//   fragment-ordered buffers:
//   Qf/Kf (B/A-frag): [bh][qb32(32)][ks(4)][lane(64)][8]
//   Vf (A-frag, V^T): [bh][kt64(16)][ks(4)][cb(2)][lane(64)][8]
// MODE 1: proj epilogue (fp32 out = acc + bias + residual)
template <int MODE>
__global__ __launch_bounds__(256) void gemm_nt_kernel(
    const unsigned short* __restrict__ A, const unsigned short* __restrict__ Bw,
    const float* __restrict__ bias, unsigned short* __restrict__ qfb,
    unsigned short* __restrict__ kfb, unsigned short* __restrict__ vfb,
    const float* __restrict__ xres, float* __restrict__ out) {
  const int b = blockIdx.z;
  const int m0 = blockIdx.y * 128;
  const int n0 = blockIdx.x * 128;
  const int tid = threadIdx.x;
  const int w = tid >> 6, ln = tid & 63;
  const int r15 = ln & 15, r4 = ln >> 4;

  __shared__ __attribute__((aligned(16))) char smem[40960];
  unsigned short* As = (unsigned short*)smem;            // staging 16KB
  unsigned short* Bs = (unsigned short*)(smem + 16384);  // staging 16KB

  const unsigned short* Ab = A + (((size_t)(b * T_ + m0)) << 9);
  const unsigned short* Bb = Bw + ((size_t)n0 << 9);

  f32x4 acc[4][4] = {};
  const int wm = (w >> 1) << 6, wn = (w & 1) << 6;

  for (int kt = 0; kt < 8; ++kt) {
    const int k0 = kt << 6;
    __syncthreads();
#pragma unroll
    for (int j = 0; j < 4; ++j) {
      const int slot = (j << 6) + ln;
      const int row = slot >> 3;
      const int chg = (slot & 7) ^ (row & 7);   // pre-swizzled source chunk
      async16(Ab + (((size_t)(w * 32 + row)) << 9) + k0 + chg * 8,
              (char*)As + w * 4096 + j * 1024);
      async16(Bb + (((size_t)(w * 32 + row)) << 9) + k0 + chg * 8,
              (char*)Bs + w * 4096 + j * 1024);
    }
    __syncthreads();
#pragma unroll
    for (int kk = 0; kk < 2; ++kk) {
      bf16x8 af[4], bfr[4];
#pragma unroll
      for (int i = 0; i < 4; ++i) {
        const int ra = wm + i * 16 + r15;
        const int ch = r4 + kk * 4;
        af[i] = *(const bf16x8*)((const char*)As + ra * 128 + ((ch ^ (ra & 7)) << 4));
        const int rb = wn + i * 16 + r15;
        bfr[i] = *(const bf16x8*)((const char*)Bs + rb * 128 + ((ch ^ (rb & 7)) << 4));
      }
#pragma unroll
      for (int i = 0; i < 4; ++i)
#pragma unroll
        for (int j = 0; j < 4; ++j)
          acc[i][j] = mfma_bf16(af[i], bfr[j], acc[i][j]);
    }
  }

  if constexpr (MODE == 0) {
    __syncthreads();  // staging reads done; LDS reused by epilogue
    const int seg = w & 1;               // this wave's 64-col segment
    const int typ3 = (n0 >> 7) % 3;      // 0:{q,k} 1:{v,q} 2:{k,v}
    int st;                              // 0=q 1=k 2=v
    if (typ3 == 0) st = seg;
    else if (typ3 == 1) st = seg ? 0 : 2;
    else st = seg ? 2 : 1;
    const int hseg = (n0 + seg * 64) / 192;
    char* segp = smem + seg * 20480;
    const int q5 = ln & 31, hi = ln >> 5;

    if (st < 2) {
      // [t(128)][c(80 padded)] bf16
      unsigned short* qkL = (unsigned short*)segp;
      const float scl = (st == 0) ? SCLF : 1.f;
#pragma unroll
      for (int j = 0; j < 4; ++j) {
        const int c = j * 16 + r15;
        const float bsv = bias[n0 + seg * 64 + c];
#pragma unroll
        for (int i = 0; i < 4; ++i) {
          const int t0 = wm + i * 16 + r4 * 4;
#pragma unroll
          for (int r = 0; r < 4; ++r)
            qkL[(t0 + r) * 80 + c] = f2bf((acc[i][j][r] + bsv) * scl);
        }
      }
      __syncthreads();
      unsigned short* dst = (st == 0) ? qfb : kfb;
      const size_t hb = ((size_t)(b * NH_ + hseg)) << 16;
#pragma unroll
      for (int u = 0; u < 8; ++u) {
        const int qbl = (w >> 1) * 2 + (u >> 2);   // local 32-row block
        const int ks = u & 3;
        bf16x8 val = *(const bf16x8*)&qkL[(qbl * 32 + q5) * 80 + ks * 16 + hi * 8];
        *(bf16x8*)&dst[hb + ((((m0 >> 5) + qbl) * 4 + ks) * 64 + ln) * 8] = val;
      }
    } else {
      // [ch(64)][t(144 padded)] bf16 (transposed)
      unsigned short* vL = (unsigned short*)segp;
#pragma unroll
      for (int j = 0; j < 4; ++j) {
        const int c = j * 16 + r15;
        const float bsv = bias[n0 + seg * 64 + c];
#pragma unroll
        for (int i = 0; i < 4; ++i) {
          const int t0 = wm + i * 16 + r4 * 4;
          u32x2 pk;
          pk.x = cvtpk_bf16(acc[i][j][0] + bsv, acc[i][j][1] + bsv);
          pk.y = cvtpk_bf16(acc[i][j][2] + bsv, acc[i][j][3] + bsv);
          *(u32x2*)&vL[c * 144 + t0] = pk;
        }
      }
      __syncthreads();
      const size_t hb = ((size_t)(b * NH_ + hseg)) << 16;
      const int ktl = w >> 1;                      // local 64-key tile
#pragma unroll
      for (int u = 0; u < 8; ++u) {
        const int ks = u >> 1, cb = u & 1;
        bf16x8 val = *(const bf16x8*)&vL[(cb * 32 + q5) * 144 +
                                         ktl * 64 + ks * 16 + hi * 8];
        *(bf16x8*)&vfb[hb + ((((m0 >> 6) + ktl) * 8 + ks * 2 + cb) * 64 + ln) * 8] = val;
      }
    }
  } else {
#pragma unroll
    for (int i = 0; i < 4; ++i) {
      const int t = m0 + wm + i * 16 + r4 * 4;
#pragma unroll
      for (int j = 0; j < 4; ++j) {
        const int o = n0 + wn + j * 16 + r15;
        const float bsv = bias[o];
        const size_t base = (((size_t)(b * C_ + o)) << 10) + t;
        const float4 xr = *(const float4*)&xres[base];
        float4 ov;
        ov.x = acc[i][j][0] + bsv + xr.x;
        ov.y = acc[i][j][1] + bsv + xr.y;
        ov.z = acc[i][j][2] + bsv + xr.z;
        ov.w = acc[i][j][3] + bsv + xr.w;
        *(float4*)&out[base] = ov;
      }
    }
  }
}

// ---------------- flash attention v11: LDS K/V pipeline, prefetch depth 2 ----------------
// vs R14 (passing): 3 LDS buffers (48KB), steady state keeps 12 loads in
// flight; vmcnt(8) means tile t's loads were issued TWO iterations (~1800
// compute-cycles) earlier -> covers HBM-latency tiles. Q loads moved before
// staging so the vmcnt queue arithmetic stays exact. Compute code unchanged.
__global__ __launch_bounds__(256) void attn_kernel(
    const unsigned short* __restrict__ Qf, const unsigned short* __restrict__ Kf,
    const unsigned short* __restrict__ Vf, unsigned short* __restrict__ aT) {
  const int lin = blockIdx.x;                   // 512 blocks
  const int bh = (lin & 7) * 16 + (lin >> 5);   // same bh -> same lin%8 -> same XCD
  const int qt = (lin >> 3) & 3;                // 4 x 256-query tiles
  const int b = bh >> 3, h = bh & 7;
  const int tid = threadIdx.x;
  const int w = tid >> 6, ln = tid & 63;
  const int q5 = ln & 31, hi = ln >> 5;

  __shared__ __attribute__((aligned(16))) unsigned short Ks[3][4096];  // 8KB/buf
  __shared__ __attribute__((aligned(16))) unsigned short Vs[3][4096];

  const unsigned short* qb_ = Qf + ((size_t)bh << 16);
  const unsigned short* kb = Kf + ((size_t)bh << 16);
  const unsigned short* vb = Vf + ((size_t)bh << 16);
  const int qw0 = qt * 8 + w * 2;   // first of this wave's two 32-q blocks

  // Q -> registers FIRST (oldest in the vmcnt queue)
  bf16x8 qf[2][4];
#pragma unroll
  for (int qb = 0; qb < 2; ++qb)
#pragma unroll
    for (int ks = 0; ks < 4; ++ks)
      qf[qb][ks] = *(const bf16x8*)(qb_ + ((((qw0 + qb) * 4 + ks) * 64 + ln) << 3));

  // staging role: waves 0,1 -> K halves; waves 2,3 -> V halves (4KB each)
  const unsigned short* sgb = (w < 2) ? kb : vb;
  const int shalf = (w & 1) * 2048;
  char* sdst = (char*)(w < 2 ? Ks[0] : Vs[0]) + (w & 1) * 4096;  // buffer 0 base

  // prologue: stage tiles 0 and 1 (4 async16/wave each)
#pragma unroll
  for (int j = 0; j < 4; ++j)
    async16(sgb + shalf + j * 512 + ln * 8, sdst + j * 1024);
#pragma unroll
  for (int j = 0; j < 4; ++j)
    async16(sgb + 4096 + shalf + j * 512 + ln * 8, sdst + 8192 + j * 1024);

  float l_run[2] = {0.f, 0.f};
  f32x16 acc[2][2] = {};   // [qb][cb]

  for (int t = 0; t < 16; ++t) {
    const int cur = t % 3;
    // A: stage tile t+2 into buffer (t+2)%3 (readers finished at iter t-1)
    if (t < 14) {
      const int nb = (t + 2) % 3;
      const int nt = (t + 2) * 4096;
#pragma unroll
      for (int j = 0; j < 4; ++j)
        async16(sgb + nt + shalf + j * 512 + ln * 8,
                (char*)(w < 2 ? Ks[nb] : Vs[nb]) + (w & 1) * 4096 + j * 1024);
      __builtin_amdgcn_sched_barrier(0);
      asm volatile("s_waitcnt vmcnt(8)" ::: "memory");
    } else if (t == 14) {
      __builtin_amdgcn_sched_barrier(0);
      asm volatile("s_waitcnt vmcnt(4)" ::: "memory");
    } else {
      __builtin_amdgcn_sched_barrier(0);
      asm volatile("s_waitcnt vmcnt(0)" ::: "memory");
    }
    // B: tile t staged everywhere; no reader left on the stage target
    __builtin_amdgcn_s_barrier();
    asm volatile("" ::: "memory");
    __builtin_amdgcn_sched_barrier(0);

    // K/V fragments from LDS
    bf16x8 kf[2][4], vf[2][4];
#pragma unroll
    for (int k2 = 0; k2 < 2; ++k2)
#pragma unroll
      for (int ks = 0; ks < 4; ++ks)
        kf[k2][ks] = *(const bf16x8*)((const char*)Ks[cur] +
                                      (((k2 * 4 + ks) << 10) + ln * 16));
#pragma unroll
    for (int cb = 0; cb < 2; ++cb)
#pragma unroll
      for (int ks = 0; ks < 4; ++ks)
        vf[cb][ks] = *(const bf16x8*)((const char*)Vs[cur] +
                                      (((ks * 2 + cb) << 10) + ln * 16));

    // D1: S^T = K.Q for both q-blocks
    f32x16 s[2][2] = {};   // [qb][k2]
    __builtin_amdgcn_s_setprio(1);
#pragma unroll
    for (int qb = 0; qb < 2; ++qb)
#pragma unroll
      for (int k2 = 0; k2 < 2; ++k2)
#pragma unroll
        for (int ks = 0; ks < 4; ++ks)
          s[qb][k2] = mfma32_bf16(kf[k2][ks], qf[qb][ks], s[qb][k2]);
    __builtin_amdgcn_s_setprio(0);

    // D2+D3 per q-block: exp, tree-sum, pack/permlane, PV
#pragma unroll
    for (int qb = 0; qb < 2; ++qb) {
      float pe[32];
#pragma unroll
      for (int u = 0; u < 16; ++u)
        pe[u] = __builtin_amdgcn_exp2f(s[qb][0][u]);
#pragma unroll
      for (int u = 0; u < 16; ++u)
        pe[16 + u] = __builtin_amdgcn_exp2f(s[qb][1][u]);

      float sm[16];
#pragma unroll
      for (int m = 0; m < 16; ++m) sm[m] = pe[2 * m] + pe[2 * m + 1];
#pragma unroll
      for (int d = 8; d; d >>= 1)
#pragma unroll
        for (int m = 0; m < 8; ++m)
          if (m < d) sm[m] += sm[m + d];
      l_run[qb] += sm[0];   // cross-half shfl deferred to epilogue

      bf16x8 pf[4];
#pragma unroll
      for (int ks = 0; ks < 4; ++ks) {
        const float* ps = pe + ks * 8;
        uint32_t Aw = cvtpk_bf16(ps[0], ps[1]);
        uint32_t Bw2 = cvtpk_bf16(ps[2], ps[3]);
        uint32_t Cw = cvtpk_bf16(ps[4], ps[5]);
        uint32_t Dw = cvtpk_bf16(ps[6], ps[7]);
        swap32(Aw, Cw);    // Aw -> W0, Cw -> W2
        swap32(Bw2, Dw);   // Bw2 -> W1, Dw -> W3
        union { uint32_t u[4]; bf16x8 v; } cv;
        cv.u[0] = Aw; cv.u[1] = Bw2; cv.u[2] = Cw; cv.u[3] = Dw;
        pf[ks] = cv.v;
      }

      __builtin_amdgcn_s_setprio(1);
#pragma unroll
      for (int cb = 0; cb < 2; ++cb)
#pragma unroll
        for (int ks = 0; ks < 4; ++ks)
          acc[qb][cb] = mfma32_bf16(vf[cb][ks], pf[ks], acc[qb][cb]);
      __builtin_amdgcn_s_setprio(0);
    }

    // E: all waves done reading buffer cur before iter t+1 stages into (t+3)%3
    __builtin_amdgcn_sched_barrier(0);
    __builtin_amdgcn_s_barrier();
    asm volatile("" ::: "memory");
  }

#pragma unroll
  for (int qb = 0; qb < 2; ++qb) {
    const float l = l_run[qb] + __shfl_xor(l_run[qb], 32);
    const float inv = 1.f / l;
    const size_t rowb = ((size_t)(b * T_ + (qw0 + qb) * 32 + q5)) << 9;
#pragma unroll
    for (int cb = 0; cb < 2; ++cb)
#pragma unroll
      for (int m = 0; m < 4; ++m) {
        u32x2 o;
        o.x = cvtpk_bf16(acc[qb][cb][4 * m] * inv, acc[qb][cb][4 * m + 1] * inv);
        o.y = cvtpk_bf16(acc[qb][cb][4 * m + 2] * inv, acc[qb][cb][4 * m + 3] * inv);
        *(u32x2*)&aT[rowb + h * 64 + cb * 32 + 8 * m + 4 * hi] = o;
      }
  }
}

extern "C" void kernel_launch(void* const* d_in, const int* in_sizes, int n_in,
                              void* d_out, int out_size, void* d_ws, size_t ws_size,
                              hipStream_t stream) {
  (void)in_sizes; (void)n_in; (void)out_size; (void)ws_size;
  const float* x      = (const float*)d_in[0];
  const float* gn_w   = (const float*)d_in[1];
  const float* gn_b   = (const float*)d_in[2];
  const float* qkv_w  = (const float*)d_in[3];
  const float* qkv_b  = (const float*)d_in[4];
  const float* proj_w = (const float*)d_in[5];
  const float* proj_b = (const float*)d_in[6];
  float* out = (float*)d_out;

  char* ws = (char*)d_ws;
  unsigned short* wq  = (unsigned short*)(ws);             // 1536x512 bf16
  unsigned short* wp  = (unsigned short*)(ws + 1572864);   // 512x512 bf16
  unsigned short* xnT = (unsigned short*)(ws + 2097152);   // [16][1024][512] bf16 (also aT)
  unsigned short* Qf  = (unsigned short*)(ws + 18874368);  // frag-ordered, 16MB
  unsigned short* Kf  = (unsigned short*)(ws + 35651584);  // frag-ordered, 16MB
  unsigned short* Vf  = (unsigned short*)(ws + 52428800);  // frag-ordered, 16MB

  convert_w_kernel<<<1024, 256, 0, stream>>>(qkv_w, proj_w, wq, wp);
  groupnorm_kernel<<<512, 256, 0, stream>>>(x, gn_w, gn_b, xnT);
  gemm_nt_kernel<0><<<dim3(12, 8, 16), 256, 0, stream>>>(xnT, wq, qkv_b, Qf, Kf, Vf,
                                                         nullptr, nullptr);
  attn_kernel<<<512, 256, 0, stream>>>(Qf, Kf, Vf, xnT /*aT alias*/);
  gemm_nt_kernel<1><<<dim3(4, 8, 16), 256, 0, stream>>>(xnT, wp, proj_b, nullptr,
                                                        nullptr, nullptr, x, out);
}

// Round 16
// 126.194 us; speedup vs baseline: 1.0008x; 1.0008x over previous
//
#include <hip/hip_runtime.h>
#include <hip/hip_bf16.h>
#include <stdint.h>

#define B_ 16
#define C_ 512
#define T_ 1024
#define NH_ 8

typedef __attribute__((ext_vector_type(8))) short bf16x8;
typedef __attribute__((ext_vector_type(4))) float f32x4;
typedef __attribute__((ext_vector_type(16))) float f32x16;
typedef __attribute__((ext_vector_type(4))) unsigned short us4;
typedef __attribute__((ext_vector_type(4))) uint32_t u32x4;
typedef __attribute__((ext_vector_type(2))) uint32_t u32x2;

__device__ __forceinline__ unsigned short f2bf(float f) {
  union { float f; uint32_t u; } v; v.f = f;
  uint32_t r = v.u + 0x7FFFu + ((v.u >> 16) & 1u);
  return (unsigned short)(r >> 16);
}

__device__ __forceinline__ uint32_t cvtpk_bf16(float lo, float hi) {
  uint32_t r;
  asm("v_cvt_pk_bf16_f32 %0, %1, %2" : "=v"(r) : "v"(lo), "v"(hi));
  return r;
}

__device__ __forceinline__ f32x4 mfma_bf16(bf16x8 a, bf16x8 b, f32x4 c) {
  asm("v_mfma_f32_16x16x32_bf16 %0, %1, %2, %0" : "+v"(c) : "v"(a), "v"(b));
  return c;
}

__device__ __forceinline__ f32x16 mfma32_bf16(bf16x8 a, bf16x8 b, f32x16 c) {
  asm("v_mfma_f32_32x32x16_bf16 %0, %1, %2, %0" : "+v"(c) : "v"(a), "v"(b));
  return c;
}

// (a,b) -> a' = {a.lo32, b.lo32}, b' = {a.hi32, b.hi32}
__device__ __forceinline__ void swap32(uint32_t& a, uint32_t& b) {
  asm("v_permlane32_swap_b32 %0, %1" : "+v"(a), "+v"(b));
}

typedef const __attribute__((address_space(1))) uint32_t* gas1_t;
typedef __attribute__((address_space(3))) uint32_t* las3_t;

// async global->LDS, 16B per lane; lds dest = wave-uniform base + lane*16
__device__ __forceinline__ void async16(const void* g, void* lds) {
  __builtin_amdgcn_global_load_lds((gas1_t)(uintptr_t)g,
                                   (las3_t)(uint32_t)(uintptr_t)lds, 16, 0, 0);
}

// q pre-scale folded into QKV epilogue: scale^2 * log2(e)
#define SCLF 0.18033688011112044f

// ---------------- weight conversion fp32 -> bf16 ----------------
__global__ __launch_bounds__(256) void convert_w_kernel(
    const float* __restrict__ qkv_w, const float* __restrict__ proj_w,
    unsigned short* __restrict__ wq, unsigned short* __restrict__ wp) {
  int i = blockIdx.x * 256 + threadIdx.x;  // float4 index, 262144 total
  const float4* src;
  unsigned short* dst;
  int rel = i;
  if (i < 196608) { src = (const float4*)qkv_w; dst = wq; }
  else            { src = (const float4*)proj_w; dst = wp; rel = i - 196608; }
  float4 v = src[rel];
  us4 o;
  o.x = f2bf(v.x); o.y = f2bf(v.y); o.z = f2bf(v.z); o.w = f2bf(v.w);
  *(us4*)&dst[(size_t)rel * 4] = o;
}

// ---------------- GroupNorm, single pass, register-resident ----------------
__global__ __launch_bounds__(256) void groupnorm_kernel(
    const float* __restrict__ x, const float* __restrict__ gn_w,
    const float* __restrict__ gn_b, unsigned short* __restrict__ xnT) {
  const int blk = blockIdx.x;   // b*32+g
  const int b = blk >> 5, g = blk & 31;
  const int tid = threadIdx.x;
  const float4* x4 = (const float4*)(x + (((size_t)(b * C_ + g * 16)) << 10));

  float4 v[16];
  float s1 = 0.f, s2 = 0.f;
#pragma unroll
  for (int i = 0; i < 16; ++i) {
    v[i] = x4[tid + i * 256];
    s1 += v[i].x + v[i].y + v[i].z + v[i].w;
    s2 += v[i].x * v[i].x + v[i].y * v[i].y + v[i].z * v[i].z + v[i].w * v[i].w;
  }
#pragma unroll
  for (int m = 32; m; m >>= 1) { s1 += __shfl_xor(s1, m); s2 += __shfl_xor(s2, m); }

  __shared__ float r1[4], r2[4], stats[2];
  const int wv = tid >> 6;
  if ((tid & 63) == 0) { r1[wv] = s1; r2[wv] = s2; }
  __syncthreads();
  if (tid == 0) {
    float a = r1[0] + r1[1] + r1[2] + r1[3];
    float q = r2[0] + r2[1] + r2[2] + r2[3];
    float mean = a * (1.f / 16384.f);
    float var = q * (1.f / 16384.f) - mean * mean;
    stats[0] = mean;
    stats[1] = rsqrtf(var + 1e-5f);
  }
  __syncthreads();
  const float mean = stats[0], rsig = stats[1];

  float wc[16], bc[16];
#pragma unroll
  for (int c = 0; c < 16; ++c) {
    const float w0 = gn_w[g * 16 + c] * rsig;
    wc[c] = w0;
    bc[c] = gn_b[g * 16 + c] - mean * w0;
  }
#pragma unroll
  for (int r = 0; r < 4; ++r) {
    uint32_t o[8];
#pragma unroll
    for (int c2 = 0; c2 < 8; ++c2) {
      const float a = ((const float*)&v[2 * c2])[r] * wc[2 * c2] + bc[2 * c2];
      const float q = ((const float*)&v[2 * c2 + 1])[r] * wc[2 * c2 + 1] + bc[2 * c2 + 1];
      o[c2] = cvtpk_bf16(a, q);
    }
    unsigned short* dst = &xnT[(((size_t)(b * T_ + tid * 4 + r)) << 9) + g * 16];
    u32x4 lo; lo.x = o[0]; lo.y = o[1]; lo.z = o[2]; lo.w = o[3];
    u32x4 hi; hi.x = o[4]; hi.y = o[5]; hi.z = o[6]; hi.w = o[7];
    *(u32x4*)dst = lo;
    *(u32x4*)(dst + 8) = hi;
  }
}

// ---------------- GEMM: D[m=t][n=o] = sum_k A[t][k] * Bw[o][k] ----------------
// MODE 0: epilogue routes through LDS -> coalesced 1KB stores into 32x32-MFMA
//   fragment-ordered buffers:
//   Qf/Kf (B/A-frag): [bh][qb32(32)][ks(4)][lane(64)][8]
//   Vf (A-frag, V^T): [bh][kt64(16)][ks(4)][cb(2)][lane(64)][8]
// MODE 1: proj epilogue (fp32 out = acc + bias + residual)
template <int MODE>
__global__ __launch_bounds__(256) void gemm_nt_kernel(
    const unsigned short* __restrict__ A, const unsigned short* __restrict__ Bw,
    const float* __restrict__ bias, unsigned short* __restrict__ qfb,
    unsigned short* __restrict__ kfb, unsigned short* __restrict__ vfb,
    const float* __restrict__ xres, float* __restrict__ out) {
  const int b = blockIdx.z;
  const int m0 = blockIdx.y * 128;
  const int n0 = blockIdx.x * 128;
  const int tid = threadIdx.x;
  const int w = tid >> 6, ln = tid & 63;
  const int r15 = ln & 15, r4 = ln >> 4;

  __shared__ __attribute__((aligned(16))) char smem[40960];
  unsigned short* As = (unsigned short*)smem;            // staging 16KB
  unsigned short* Bs = (unsigned short*)(smem + 16384);  // staging 16KB

  const unsigned short* Ab = A + (((size_t)(b * T_ + m0)) << 9);
  const unsigned short* Bb = Bw + ((size_t)n0 << 9);

  f32x4 acc[4][4] = {};
  const int wm = (w >> 1) << 6, wn = (w & 1) << 6;

  for (int kt = 0; kt < 8; ++kt) {
    const int k0 = kt << 6;
    __syncthreads();
#pragma unroll
    for (int j = 0; j < 4; ++j) {
      const int slot = (j << 6) + ln;
      const int row = slot >> 3;
      const int chg = (slot & 7) ^ (row & 7);   // pre-swizzled source chunk
      async16(Ab + (((size_t)(w * 32 + row)) << 9) + k0 + chg * 8,
              (char*)As + w * 4096 + j * 1024);
      async16(Bb + (((size_t)(w * 32 + row)) << 9) + k0 + chg * 8,
              (char*)Bs + w * 4096 + j * 1024);
    }
    __syncthreads();
#pragma unroll
    for (int kk = 0; kk < 2; ++kk) {
      bf16x8 af[4], bfr[4];
#pragma unroll
      for (int i = 0; i < 4; ++i) {
        const int ra = wm + i * 16 + r15;
        const int ch = r4 + kk * 4;
        af[i] = *(const bf16x8*)((const char*)As + ra * 128 + ((ch ^ (ra & 7)) << 4));
        const int rb = wn + i * 16 + r15;
        bfr[i] = *(const bf16x8*)((const char*)Bs + rb * 128 + ((ch ^ (rb & 7)) << 4));
      }
#pragma unroll
      for (int i = 0; i < 4; ++i)
#pragma unroll
        for (int j = 0; j < 4; ++j)
          acc[i][j] = mfma_bf16(af[i], bfr[j], acc[i][j]);
    }
  }

  if constexpr (MODE == 0) {
    __syncthreads();  // staging reads done; LDS reused by epilogue
    const int seg = w & 1;               // this wave's 64-col segment
    const int typ3 = (n0 >> 7) % 3;      // 0:{q,k} 1:{v,q} 2:{k,v}
    int st;                              // 0=q 1=k 2=v
    if (typ3 == 0) st = seg;
    else if (typ3 == 1) st = seg ? 0 : 2;
    else st = seg ? 2 : 1;
    const int hseg = (n0 + seg * 64) / 192;
    char* segp = smem + seg * 20480;
    const int q5 = ln & 31, hi = ln >> 5;

    if (st < 2) {
      // [t(128)][c(80 padded)] bf16
      unsigned short* qkL = (unsigned short*)segp;
      const float scl = (st == 0) ? SCLF : 1.f;
#pragma unroll
      for (int j = 0; j < 4; ++j) {
        const int c = j * 16 + r15;
        const float bsv = bias[n0 + seg * 64 + c];
#pragma unroll
        for (int i = 0; i < 4; ++i) {
          const int t0 = wm + i * 16 + r4 * 4;
#pragma unroll
          for (int r = 0; r < 4; ++r)
            qkL[(t0 + r) * 80 + c] = f2bf((acc[i][j][r] + bsv) * scl);
        }
      }
      __syncthreads();
      unsigned short* dst = (st == 0) ? qfb : kfb;
      const size_t hb = ((size_t)(b * NH_ + hseg)) << 16;
#pragma unroll
      for (int u = 0; u < 8; ++u) {
        const int qbl = (w >> 1) * 2 + (u >> 2);   // local 32-row block
        const int ks = u & 3;
        bf16x8 val = *(const bf16x8*)&qkL[(qbl * 32 + q5) * 80 + ks * 16 + hi * 8];
        *(bf16x8*)&dst[hb + ((((m0 >> 5) + qbl) * 4 + ks) * 64 + ln) * 8] = val;
      }
    } else {
      // [ch(64)][t(144 padded)] bf16 (transposed)
      unsigned short* vL = (unsigned short*)segp;
#pragma unroll
      for (int j = 0; j < 4; ++j) {
        const int c = j * 16 + r15;
        const float bsv = bias[n0 + seg * 64 + c];
#pragma unroll
        for (int i = 0; i < 4; ++i) {
          const int t0 = wm + i * 16 + r4 * 4;
          u32x2 pk;
          pk.x = cvtpk_bf16(acc[i][j][0] + bsv, acc[i][j][1] + bsv);
          pk.y = cvtpk_bf16(acc[i][j][2] + bsv, acc[i][j][3] + bsv);
          *(u32x2*)&vL[c * 144 + t0] = pk;
        }
      }
      __syncthreads();
      const size_t hb = ((size_t)(b * NH_ + hseg)) << 16;
      const int ktl = w >> 1;                      // local 64-key tile
#pragma unroll
      for (int u = 0; u < 8; ++u) {
        const int ks = u >> 1, cb = u & 1;
        bf16x8 val = *(const bf16x8*)&vL[(cb * 32 + q5) * 144 +
                                         ktl * 64 + ks * 16 + hi * 8];
        *(bf16x8*)&vfb[hb + ((((m0 >> 6) + ktl) * 8 + ks * 2 + cb) * 64 + ln) * 8] = val;
      }
    }
  } else {
#pragma unroll
    for (int i = 0; i < 4; ++i) {
      const int t = m0 + wm + i * 16 + r4 * 4;
#pragma unroll
      for (int j = 0; j < 4; ++j) {
        const int o = n0 + wn + j * 16 + r15;
        const float bsv = bias[o];
        const size_t base = (((size_t)(b * C_ + o)) << 10) + t;
        const float4 xr = *(const float4*)&xres[base];
        float4 ov;
        ov.x = acc[i][j][0] + bsv + xr.x;
        ov.y = acc[i][j][1] + bsv + xr.y;
        ov.z = acc[i][j][2] + bsv + xr.z;
        ov.w = acc[i][j][3] + bsv + xr.w;
        *(float4*)&out[base] = ov;
      }
    }
  }
}

// ---------------- flash attention v11: LDS K/V pipeline, prefetch depth 2 ----------------
// vs R14 (passing): 3 LDS buffers (48KB), steady state keeps 12 loads in
// flight; vmcnt(8) means tile t's loads were issued TWO iterations (~1800
// compute-cycles) earlier -> covers HBM-latency tiles. Q loads moved before
// staging so the vmcnt queue arithmetic stays exact. Compute code unchanged.
__global__ __launch_bounds__(256) void attn_kernel(
    const unsigned short* __restrict__ Qf, const unsigned short* __restrict__ Kf,
    const unsigned short* __restrict__ Vf, unsigned short* __restrict__ aT) {
  const int lin = blockIdx.x;                   // 512 blocks
  const int bh = (lin & 7) * 16 + (lin >> 5);   // same bh -> same lin%8 -> same XCD
  const int qt = (lin >> 3) & 3;                // 4 x 256-query tiles
  const int b = bh >> 3, h = bh & 7;
  const int tid = threadIdx.x;
  const int w = tid >> 6, ln = tid & 63;
  const int q5 = ln & 31, hi = ln >> 5;

  __shared__ __attribute__((aligned(16))) unsigned short Ks[3][4096];  // 8KB/buf
  __shared__ __attribute__((aligned(16))) unsigned short Vs[3][4096];

  const unsigned short* qb_ = Qf + ((size_t)bh << 16);
  const unsigned short* kb = Kf + ((size_t)bh << 16);
  const unsigned short* vb = Vf + ((size_t)bh << 16);
  const int qw0 = qt * 8 + w * 2;   // first of this wave's two 32-q blocks

  // Q -> registers FIRST (oldest in the vmcnt queue)
  bf16x8 qf[2][4];
#pragma unroll
  for (int qb = 0; qb < 2; ++qb)
#pragma unroll
    for (int ks = 0; ks < 4; ++ks)
      qf[qb][ks] = *(const bf16x8*)(qb_ + ((((qw0 + qb) * 4 + ks) * 64 + ln) << 3));

  // staging role: waves 0,1 -> K halves; waves 2,3 -> V halves (4KB each)
  const unsigned short* sgb = (w < 2) ? kb : vb;
  const int shalf = (w & 1) * 2048;
  char* sdst = (char*)(w < 2 ? Ks[0] : Vs[0]) + (w & 1) * 4096;  // buffer 0 base

  // prologue: stage tiles 0 and 1 (4 async16/wave each)
#pragma unroll
  for (int j = 0; j < 4; ++j)
    async16(sgb + shalf + j * 512 + ln * 8, sdst + j * 1024);
#pragma unroll
  for (int j = 0; j < 4; ++j)
    async16(sgb + 4096 + shalf + j * 512 + ln * 8, sdst + 8192 + j * 1024);

  float l_run[2] = {0.f, 0.f};
  f32x16 acc[2][2] = {};   // [qb][cb]

  for (int t = 0; t < 16; ++t) {
    const int cur = t % 3;
    // A: stage tile t+2 into buffer (t+2)%3 (readers finished at iter t-1)
    if (t < 14) {
      const int nb = (t + 2) % 3;
      const int nt = (t + 2) * 4096;
#pragma unroll
      for (int j = 0; j < 4; ++j)
        async16(sgb + nt + shalf + j * 512 + ln * 8,
                (char*)(w < 2 ? Ks[nb] : Vs[nb]) + (w & 1) * 4096 + j * 1024);
      __builtin_amdgcn_sched_barrier(0);
      asm volatile("s_waitcnt vmcnt(8)" ::: "memory");
    } else if (t == 14) {
      __builtin_amdgcn_sched_barrier(0);
      asm volatile("s_waitcnt vmcnt(4)" ::: "memory");
    } else {
      __builtin_amdgcn_sched_barrier(0);
      asm volatile("s_waitcnt vmcnt(0)" ::: "memory");
    }
    // B: tile t staged everywhere; no reader left on the stage target
    __builtin_amdgcn_s_barrier();
    asm volatile("" ::: "memory");
    __builtin_amdgcn_sched_barrier(0);

    // K/V fragments from LDS
    bf16x8 kf[2][4], vf[2][4];
#pragma unroll
    for (int k2 = 0; k2 < 2; ++k2)
#pragma unroll
      for (int ks = 0; ks < 4; ++ks)
        kf[k2][ks] = *(const bf16x8*)((const char*)Ks[cur] +
                                      (((k2 * 4 + ks) << 10) + ln * 16));
#pragma unroll
    for (int cb = 0; cb < 2; ++cb)
#pragma unroll
      for (int ks = 0; ks < 4; ++ks)
        vf[cb][ks] = *(const bf16x8*)((const char*)Vs[cur] +
                                      (((ks * 2 + cb) << 10) + ln * 16));

    // D1: S^T = K.Q for both q-blocks
    f32x16 s[2][2] = {};   // [qb][k2]
    __builtin_amdgcn_s_setprio(1);
#pragma unroll
    for (int qb = 0; qb < 2; ++qb)
#pragma unroll
      for (int k2 = 0; k2 < 2; ++k2)
#pragma unroll
        for (int ks = 0; ks < 4; ++ks)
          s[qb][k2] = mfma32_bf16(kf[k2][ks], qf[qb][ks], s[qb][k2]);
    __builtin_amdgcn_s_setprio(0);

    // D2+D3 per q-block: exp, tree-sum, pack/permlane, PV
#pragma unroll
    for (int qb = 0; qb < 2; ++qb) {
      float pe[32];
#pragma unroll
      for (int u = 0; u < 16; ++u)
        pe[u] = __builtin_amdgcn_exp2f(s[qb][0][u]);
#pragma unroll
      for (int u = 0; u < 16; ++u)
        pe[16 + u] = __builtin_amdgcn_exp2f(s[qb][1][u]);

      float sm[16];
#pragma unroll
      for (int m = 0; m < 16; ++m) sm[m] = pe[2 * m] + pe[2 * m + 1];
#pragma unroll
      for (int d = 8; d; d >>= 1)
#pragma unroll
        for (int m = 0; m < 8; ++m)
          if (m < d) sm[m] += sm[m + d];
      l_run[qb] += sm[0];   // cross-half shfl deferred to epilogue

      bf16x8 pf[4];
#pragma unroll
      for (int ks = 0; ks < 4; ++ks) {
        const float* ps = pe + ks * 8;
        uint32_t Aw = cvtpk_bf16(ps[0], ps[1]);
        uint32_t Bw2 = cvtpk_bf16(ps[2], ps[3]);
        uint32_t Cw = cvtpk_bf16(ps[4], ps[5]);
        uint32_t Dw = cvtpk_bf16(ps[6], ps[7]);
        swap32(Aw, Cw);    // Aw -> W0, Cw -> W2
        swap32(Bw2, Dw);   // Bw2 -> W1, Dw -> W3
        union { uint32_t u[4]; bf16x8 v; } cv;
        cv.u[0] = Aw; cv.u[1] = Bw2; cv.u[2] = Cw; cv.u[3] = Dw;
        pf[ks] = cv.v;
      }

      __builtin_amdgcn_s_setprio(1);
#pragma unroll
      for (int cb = 0; cb < 2; ++cb)
#pragma unroll
        for (int ks = 0; ks < 4; ++ks)
          acc[qb][cb] = mfma32_bf16(vf[cb][ks], pf[ks], acc[qb][cb]);
      __builtin_amdgcn_s_setprio(0);
    }

    // E: all waves done reading buffer cur before iter t+1 stages into (t+3)%3
    __builtin_amdgcn_sched_barrier(0);
    __builtin_amdgcn_s_barrier();
    asm volatile("" ::: "memory");
  }

#pragma unroll
  for (int qb = 0; qb < 2; ++qb) {
    const float l = l_run[qb] + __shfl_xor(l_run[qb], 32);
    const float inv = 1.f / l;
    const size_t rowb = ((size_t)(b * T_ + (qw0 + qb) * 32 + q5)) << 9;
#pragma unroll
    for (int cb = 0; cb < 2; ++cb)
#pragma unroll
      for (int m = 0; m < 4; ++m) {
        u32x2 o;
        o.x = cvtpk_bf16(acc[qb][cb][4 * m] * inv, acc[qb][cb][4 * m + 1] * inv);
        o.y = cvtpk_bf16(acc[qb][cb][4 * m + 2] * inv, acc[qb][cb][4 * m + 3] * inv);
        *(u32x2*)&aT[rowb + h * 64 + cb * 32 + 8 * m + 4 * hi] = o;
      }
  }
}

extern "C" void kernel_launch(void* const* d_in, const int* in_sizes, int n_in,
                              void* d_out, int out_size, void* d_ws, size_t ws_size,
                              hipStream_t stream) {
  (void)in_sizes; (void)n_in; (void)out_size; (void)ws_size;
  const float* x      = (const float*)d_in[0];
  const float* gn_w   = (const float*)d_in[1];
  const float* gn_b   = (const float*)d_in[2];
  const float* qkv_w  = (const float*)d_in[3];
  const float* qkv_b  = (const float*)d_in[4];
  const float* proj_w = (const float*)d_in[5];
  const float* proj_b = (const float*)d_in[6];
  float* out = (float*)d_out;

  char* ws = (char*)d_ws;
  unsigned short* wq  = (unsigned short*)(ws);             // 1536x512 bf16
  unsigned short* wp  = (unsigned short*)(ws + 1572864);   // 512x512 bf16
  unsigned short* xnT = (unsigned short*)(ws + 2097152);   // [16][1024][512] bf16 (also aT)
  unsigned short* Qf  = (unsigned short*)(ws + 18874368);  // frag-ordered, 16MB
  unsigned short* Kf  = (unsigned short*)(ws + 35651584);  // frag-ordered, 16MB
  unsigned short* Vf  = (unsigned short*)(ws + 52428800);  // frag-ordered, 16MB

  convert_w_kernel<<<1024, 256, 0, stream>>>(qkv_w, proj_w, wq, wp);
  groupnorm_kernel<<<512, 256, 0, stream>>>(x, gn_w, gn_b, xnT);
  gemm_nt_kernel<0><<<dim3(12, 8, 16), 256, 0, stream>>>(xnT, wq, qkv_b, Qf, Kf, Vf,
                                                         nullptr, nullptr);
  attn_kernel<<<512, 256, 0, stream>>>(Qf, Kf, Vf, xnT /*aT alias*/);
  gemm_nt_kernel<1><<<dim3(4, 8, 16), 256, 0, stream>>>(xnT, wp, proj_b, nullptr,
                                                        nullptr, nullptr, x, out);
}

// Round 19
// 117.947 us; speedup vs baseline: 1.0708x; 1.0699x over previous
//
#include <hip/hip_runtime.h>
#include <hip/hip_bf16.h>
#include <stdint.h>

#define B_ 16
#define C_ 512
#define T_ 1024
#define NH_ 8

typedef __attribute__((ext_vector_type(8))) short bf16x8;
typedef __attribute__((ext_vector_type(4))) float f32x4;
typedef __attribute__((ext_vector_type(16))) float f32x16;
typedef __attribute__((ext_vector_type(4))) unsigned short us4;
typedef __attribute__((ext_vector_type(4))) uint32_t u32x4;
typedef __attribute__((ext_vector_type(2))) uint32_t u32x2;

__device__ __forceinline__ unsigned short f2bf(float f) {
  union { float f; uint32_t u; } v; v.f = f;
  uint32_t r = v.u + 0x7FFFu + ((v.u >> 16) & 1u);
  return (unsigned short)(r >> 16);
}

__device__ __forceinline__ uint32_t cvtpk_bf16(float lo, float hi) {
  uint32_t r;
  asm("v_cvt_pk_bf16_f32 %0, %1, %2" : "=v"(r) : "v"(lo), "v"(hi));
  return r;
}

__device__ __forceinline__ f32x4 mfma_bf16(bf16x8 a, bf16x8 b, f32x4 c) {
  asm("v_mfma_f32_16x16x32_bf16 %0, %1, %2, %0" : "+v"(c) : "v"(a), "v"(b));
  return c;
}

__device__ __forceinline__ f32x16 mfma32_bf16(bf16x8 a, bf16x8 b, f32x16 c) {
  asm("v_mfma_f32_32x32x16_bf16 %0, %1, %2, %0" : "+v"(c) : "v"(a), "v"(b));
  return c;
}

// (a,b) -> a' = {a.lo32, b.lo32}, b' = {a.hi32, b.hi32}
__device__ __forceinline__ void swap32(uint32_t& a, uint32_t& b) {
  asm("v_permlane32_swap_b32 %0, %1" : "+v"(a), "+v"(b));
}

typedef const __attribute__((address_space(1))) uint32_t* gas1_t;
typedef __attribute__((address_space(3))) uint32_t* las3_t;

// async global->LDS, 16B per lane; lds dest = wave-uniform base + lane*16
__device__ __forceinline__ void async16(const void* g, void* lds) {
  __builtin_amdgcn_global_load_lds((gas1_t)(uintptr_t)g,
                                   (las3_t)(uint32_t)(uintptr_t)lds, 16, 0, 0);
}

// q pre-scale folded into QKV epilogue: scale^2 * log2(e)
#define SCLF 0.18033688011112044f

// ---------------- weight conversion fp32 -> bf16 ----------------
__global__ __launch_bounds__(256) void convert_w_kernel(
    const float* __restrict__ qkv_w, const float* __restrict__ proj_w,
    unsigned short* __restrict__ wq, unsigned short* __restrict__ wp) {
  int i = blockIdx.x * 256 + threadIdx.x;  // float4 index, 262144 total
  const float4* src;
  unsigned short* dst;
  int rel = i;
  if (i < 196608) { src = (const float4*)qkv_w; dst = wq; }
  else            { src = (const float4*)proj_w; dst = wp; rel = i - 196608; }
  float4 v = src[rel];
  us4 o;
  o.x = f2bf(v.x); o.y = f2bf(v.y); o.z = f2bf(v.z); o.w = f2bf(v.w);
  *(us4*)&dst[(size_t)rel * 4] = o;
}

// ---------------- GroupNorm, single pass, register-resident ----------------
__global__ __launch_bounds__(256) void groupnorm_kernel(
    const float* __restrict__ x, const float* __restrict__ gn_w,
    const float* __restrict__ gn_b, unsigned short* __restrict__ xnT) {
  const int blk = blockIdx.x;   // b*32+g
  const int b = blk >> 5, g = blk & 31;
  const int tid = threadIdx.x;
  const float4* x4 = (const float4*)(x + (((size_t)(b * C_ + g * 16)) << 10));

  float4 v[16];
  float s1 = 0.f, s2 = 0.f;
#pragma unroll
  for (int i = 0; i < 16; ++i) {
    v[i] = x4[tid + i * 256];
    s1 += v[i].x + v[i].y + v[i].z + v[i].w;
    s2 += v[i].x * v[i].x + v[i].y * v[i].y + v[i].z * v[i].z + v[i].w * v[i].w;
  }
#pragma unroll
  for (int m = 32; m; m >>= 1) { s1 += __shfl_xor(s1, m); s2 += __shfl_xor(s2, m); }

  __shared__ float r1[4], r2[4], stats[2];
  const int wv = tid >> 6;
  if ((tid & 63) == 0) { r1[wv] = s1; r2[wv] = s2; }
  __syncthreads();
  if (tid == 0) {
    float a = r1[0] + r1[1] + r1[2] + r1[3];
    float q = r2[0] + r2[1] + r2[2] + r2[3];
    float mean = a * (1.f / 16384.f);
    float var = q * (1.f / 16384.f) - mean * mean;
    stats[0] = mean;
    stats[1] = rsqrtf(var + 1e-5f);
  }
  __syncthreads();
  const float mean = stats[0], rsig = stats[1];

  float wc[16], bc[16];
#pragma unroll
  for (int c = 0; c < 16; ++c) {
    const float w0 = gn_w[g * 16 + c] * rsig;
    wc[c] = w0;
    bc[c] = gn_b[g * 16 + c] - mean * w0;
  }
#pragma unroll
  for (int r = 0; r < 4; ++r) {
    uint32_t o[8];
#pragma unroll
    for (int c2 = 0; c2 < 8; ++c2) {
      const float a = ((const float*)&v[2 * c2])[r] * wc[2 * c2] + bc[2 * c2];
      const float q = ((const float*)&v[2 * c2 + 1])[r] * wc[2 * c2 + 1] + bc[2 * c2 + 1];
      o[c2] = cvtpk_bf16(a, q);
    }
    unsigned short* dst = &xnT[(((size_t)(b * T_ + tid * 4 + r)) << 9) + g * 16];
    u32x4 lo; lo.x = o[0]; lo.y = o[1]; lo.z = o[2]; lo.w = o[3];
    u32x4 hi; hi.x = o[4]; hi.y = o[5]; hi.z = o[6]; hi.w = o[7];
    *(u32x4*)dst = lo;
    *(u32x4*)(dst + 8) = hi;
  }
}

// ---------------- GEMM: D[m=t][n=o] = sum_k A[t][k] * Bw[o][k] ----------------
// MODE 0: epilogue routes through LDS -> coalesced 1KB stores into 32x32-MFMA
//   fragment-ordered buffers:
//   Qf/Kf (B/A-frag): [bh][qb32(32)][ks(4)][lane(64)][8]
//   Vf (A-frag, V^T): [bh][kt64(16)][ks(4)][cb(2)][lane(64)][8]
//   MODE 0 also applies a bijective XCD swizzle (1536 = 8*192) so each XCD
//   works on 2 contiguous batches (A+B working set ~3.5MB <= 4MB L2).
// MODE 1: proj epilogue (fp32 out = acc + bias + residual)
template <int MODE>
__global__ __launch_bounds__(256) void gemm_nt_kernel(
    const unsigned short* __restrict__ A, const unsigned short* __restrict__ Bw,
    const float* __restrict__ bias, unsigned short* __restrict__ qfb,
    unsigned short* __restrict__ kfb, unsigned short* __restrict__ vfb,
    const float* __restrict__ xres, float* __restrict__ out) {
  int bx = blockIdx.x, by = blockIdx.y, bz = blockIdx.z;
  if constexpr (MODE == 0) {
    const int lin = bx + 12 * (by + 8 * bz);       // [0,1536)
    const int swz = (lin & 7) * 192 + (lin >> 3);  // bijective permutation
    bx = swz % 12; by = (swz / 12) & 7; bz = swz / 96;
  }
  const int b = bz;
  const int m0 = by * 128;
  const int n0 = bx * 128;
  const int tid = threadIdx.x;
  const int w = tid >> 6, ln = tid & 63;
  const int r15 = ln & 15, r4 = ln >> 4;

  __shared__ __attribute__((aligned(16))) char smem[40960];
  unsigned short* As = (unsigned short*)smem;            // staging 16KB
  unsigned short* Bs = (unsigned short*)(smem + 16384);  // staging 16KB

  const unsigned short* Ab = A + (((size_t)(b * T_ + m0)) << 9);
  const unsigned short* Bb = Bw + ((size_t)n0 << 9);

  f32x4 acc[4][4] = {};
  const int wm = (w >> 1) << 6, wn = (w & 1) << 6;

  for (int kt = 0; kt < 8; ++kt) {
    const int k0 = kt << 6;
    __syncthreads();
#pragma unroll
    for (int j = 0; j < 4; ++j) {
      const int slot = (j << 6) + ln;
      const int row = slot >> 3;
      const int chg = (slot & 7) ^ (row & 7);   // pre-swizzled source chunk
      async16(Ab + (((size_t)(w * 32 + row)) << 9) + k0 + chg * 8,
              (char*)As + w * 4096 + j * 1024);
      async16(Bb + (((size_t)(w * 32 + row)) << 9) + k0 + chg * 8,
              (char*)Bs + w * 4096 + j * 1024);
    }
    __syncthreads();
#pragma unroll
    for (int kk = 0; kk < 2; ++kk) {
      bf16x8 af[4], bfr[4];
#pragma unroll
      for (int i = 0; i < 4; ++i) {
        const int ra = wm + i * 16 + r15;
        const int ch = r4 + kk * 4;
        af[i] = *(const bf16x8*)((const char*)As + ra * 128 + ((ch ^ (ra & 7)) << 4));
        const int rb = wn + i * 16 + r15;
        bfr[i] = *(const bf16x8*)((const char*)Bs + rb * 128 + ((ch ^ (rb & 7)) << 4));
      }
#pragma unroll
      for (int i = 0; i < 4; ++i)
#pragma unroll
        for (int j = 0; j < 4; ++j)
          acc[i][j] = mfma_bf16(af[i], bfr[j], acc[i][j]);
    }
  }

  if constexpr (MODE == 0) {
    __syncthreads();  // staging reads done; LDS reused by epilogue
    const int seg = w & 1;               // this wave's 64-col segment
    const int typ3 = (n0 >> 7) % 3;      // 0:{q,k} 1:{v,q} 2:{k,v}
    int st;                              // 0=q 1=k 2=v
    if (typ3 == 0) st = seg;
    else if (typ3 == 1) st = seg ? 0 : 2;
    else st = seg ? 2 : 1;
    const int hseg = (n0 + seg * 64) / 192;
    char* segp = smem + seg * 20480;
    const int q5 = ln & 31, hi = ln >> 5;

    if (st < 2) {
      // [t(128)][c(80 padded)] bf16
      unsigned short* qkL = (unsigned short*)segp;
      const float scl = (st == 0) ? SCLF : 1.f;
#pragma unroll
      for (int j = 0; j < 4; ++j) {
        const int c = j * 16 + r15;
        const float bsv = bias[n0 + seg * 64 + c];
#pragma unroll
        for (int i = 0; i < 4; ++i) {
          const int t0 = wm + i * 16 + r4 * 4;
#pragma unroll
          for (int r = 0; r < 4; ++r)
            qkL[(t0 + r) * 80 + c] = f2bf((acc[i][j][r] + bsv) * scl);
        }
      }
      __syncthreads();
      unsigned short* dst = (st == 0) ? qfb : kfb;
      const size_t hb = ((size_t)(b * NH_ + hseg)) << 16;
#pragma unroll
      for (int u = 0; u < 8; ++u) {
        const int qbl = (w >> 1) * 2 + (u >> 2);   // local 32-row block
        const int ks = u & 3;
        bf16x8 val = *(const bf16x8*)&qkL[(qbl * 32 + q5) * 80 + ks * 16 + hi * 8];
        *(bf16x8*)&dst[hb + ((((m0 >> 5) + qbl) * 4 + ks) * 64 + ln) * 8] = val;
      }
    } else {
      // [ch(64)][t(144 padded)] bf16 (transposed)
      unsigned short* vL = (unsigned short*)segp;
#pragma unroll
      for (int j = 0; j < 4; ++j) {
        const int c = j * 16 + r15;
        const float bsv = bias[n0 + seg * 64 + c];
#pragma unroll
        for (int i = 0; i < 4; ++i) {
          const int t0 = wm + i * 16 + r4 * 4;
          u32x2 pk;
          pk.x = cvtpk_bf16(acc[i][j][0] + bsv, acc[i][j][1] + bsv);
          pk.y = cvtpk_bf16(acc[i][j][2] + bsv, acc[i][j][3] + bsv);
          *(u32x2*)&vL[c * 144 + t0] = pk;
        }
      }
      __syncthreads();
      const size_t hb = ((size_t)(b * NH_ + hseg)) << 16;
      const int ktl = w >> 1;                      // local 64-key tile
#pragma unroll
      for (int u = 0; u < 8; ++u) {
        const int ks = u >> 1, cb = u & 1;
        bf16x8 val = *(const bf16x8*)&vL[(cb * 32 + q5) * 144 +
                                         ktl * 64 + ks * 16 + hi * 8];
        *(bf16x8*)&vfb[hb + ((((m0 >> 6) + ktl) * 8 + ks * 2 + cb) * 64 + ln) * 8] = val;
      }
    }
  } else {
#pragma unroll
    for (int i = 0; i < 4; ++i) {
      const int t = m0 + wm + i * 16 + r4 * 4;
#pragma unroll
      for (int j = 0; j < 4; ++j) {
        const int o = n0 + wn + j * 16 + r15;
        const float bsv = bias[o];
        const size_t base = (((size_t)(b * C_ + o)) << 10) + t;
        const float4 xr = *(const float4*)&xres[base];
        float4 ov;
        ov.x = acc[i][j][0] + bsv + xr.x;
        ov.y = acc[i][j][1] + bsv + xr.y;
        ov.z = acc[i][j][2] + bsv + xr.z;
        ov.w = acc[i][j][3] + bsv + xr.w;
        *(float4*)&out[base] = ov;
      }
    }
  }
}

// ---------------- flash attention v10: 64 q/wave + LDS K/V pipeline ----------------
// (exact R14 passing kernel) kf/vf come from LDS, staged once per block via
// global_load_lds (tile = contiguous 8KB in the fragment layout -> linear
// memcpy), double-buffered with the proven counted-vmcnt + raw-s_barrier
// schedule. All 4 waves share K/V.
__global__ __launch_bounds__(256) void attn_kernel(
    const unsigned short* __restrict__ Qf, const unsigned short* __restrict__ Kf,
    const unsigned short* __restrict__ Vf, unsigned short* __restrict__ aT) {
  const int lin = blockIdx.x;                   // 512 blocks
  const int bh = (lin & 7) * 16 + (lin >> 5);   // same bh -> same lin%8 -> same XCD
  const int qt = (lin >> 3) & 3;                // 4 x 256-query tiles
  const int b = bh >> 3, h = bh & 7;
  const int tid = threadIdx.x;
  const int w = tid >> 6, ln = tid & 63;
  const int q5 = ln & 31, hi = ln >> 5;

  __shared__ __attribute__((aligned(16))) unsigned short Ks[2][4096];  // 8KB/tile
  __shared__ __attribute__((aligned(16))) unsigned short Vs[2][4096];

  const unsigned short* qb_ = Qf + ((size_t)bh << 16);
  const unsigned short* kb = Kf + ((size_t)bh << 16);
  const unsigned short* vb = Vf + ((size_t)bh << 16);
  const int qw0 = qt * 8 + w * 2;   // first of this wave's two 32-q blocks

  // staging role: waves 0,1 -> K halves; waves 2,3 -> V halves (4KB each)
  const unsigned short* sgb = (w < 2) ? kb : vb;
  const int shalf = (w & 1) * 2048;

  // prologue: stage tile 0 (4 async16/wave), then Q -> registers
#pragma unroll
  for (int j = 0; j < 4; ++j)
    async16(sgb + shalf + j * 512 + ln * 8,
            (char*)(w < 2 ? Ks[0] : Vs[0]) + (w & 1) * 4096 + j * 1024);

  bf16x8 qf[2][4];
#pragma unroll
  for (int qb = 0; qb < 2; ++qb)
#pragma unroll
    for (int ks = 0; ks < 4; ++ks)
      qf[qb][ks] = *(const bf16x8*)(qb_ + ((((qw0 + qb) * 4 + ks) * 64 + ln) << 3));

  float l_run[2] = {0.f, 0.f};
  f32x16 acc[2][2] = {};   // [qb][cb]

  for (int t = 0; t < 16; ++t) {
    const int p = t & 1;
    // A: stage next tile into the other buffer (tile = 4096 shorts, linear)
    if (t < 15) {
      const int nt = (t + 1) * 4096;
#pragma unroll
      for (int j = 0; j < 4; ++j)
        async16(sgb + nt + shalf + j * 512 + ln * 8,
                (char*)(w < 2 ? Ks[p ^ 1] : Vs[p ^ 1]) + (w & 1) * 4096 + j * 1024);
      __builtin_amdgcn_sched_barrier(0);
      asm volatile("s_waitcnt vmcnt(4)" ::: "memory");
    } else {
      __builtin_amdgcn_sched_barrier(0);
      asm volatile("s_waitcnt vmcnt(0)" ::: "memory");
    }
    // B: tile t staged everywhere; no reader left on buffer p^1
    __builtin_amdgcn_s_barrier();
    asm volatile("" ::: "memory");
    __builtin_amdgcn_sched_barrier(0);

    // K/V fragments from LDS (same indexing as the old global reads)
    bf16x8 kf[2][4], vf[2][4];
#pragma unroll
    for (int k2 = 0; k2 < 2; ++k2)
#pragma unroll
      for (int ks = 0; ks < 4; ++ks)
        kf[k2][ks] = *(const bf16x8*)((const char*)Ks[p] +
                                      (((k2 * 4 + ks) << 10) + ln * 16));
#pragma unroll
    for (int cb = 0; cb < 2; ++cb)
#pragma unroll
      for (int ks = 0; ks < 4; ++ks)
        vf[cb][ks] = *(const bf16x8*)((const char*)Vs[p] +
                                      (((ks * 2 + cb) << 10) + ln * 16));

    // D1: S^T = K.Q for both q-blocks
    f32x16 s[2][2] = {};   // [qb][k2]
    __builtin_amdgcn_s_setprio(1);
#pragma unroll
    for (int qb = 0; qb < 2; ++qb)
#pragma unroll
      for (int k2 = 0; k2 < 2; ++k2)
#pragma unroll
        for (int ks = 0; ks < 4; ++ks)
          s[qb][k2] = mfma32_bf16(kf[k2][ks], qf[qb][ks], s[qb][k2]);
    __builtin_amdgcn_s_setprio(0);

    // D2+D3 per q-block: exp, tree-sum, pack/permlane, PV
#pragma unroll
    for (int qb = 0; qb < 2; ++qb) {
      float pe[32];
#pragma unroll
      for (int u = 0; u < 16; ++u)
        pe[u] = __builtin_amdgcn_exp2f(s[qb][0][u]);
#pragma unroll
      for (int u = 0; u < 16; ++u)
        pe[16 + u] = __builtin_amdgcn_exp2f(s[qb][1][u]);

      float sm[16];
#pragma unroll
      for (int m = 0; m < 16; ++m) sm[m] = pe[2 * m] + pe[2 * m + 1];
#pragma unroll
      for (int d = 8; d; d >>= 1)
#pragma unroll
        for (int m = 0; m < 8; ++m)
          if (m < d) sm[m] += sm[m + d];
      l_run[qb] += sm[0];   // cross-half shfl deferred to epilogue

      bf16x8 pf[4];
#pragma unroll
      for (int ks = 0; ks < 4; ++ks) {
        const float* ps = pe + ks * 8;
        uint32_t Aw = cvtpk_bf16(ps[0], ps[1]);
        uint32_t Bw2 = cvtpk_bf16(ps[2], ps[3]);
        uint32_t Cw = cvtpk_bf16(ps[4], ps[5]);
        uint32_t Dw = cvtpk_bf16(ps[6], ps[7]);
        swap32(Aw, Cw);    // Aw -> W0, Cw -> W2
        swap32(Bw2, Dw);   // Bw2 -> W1, Dw -> W3
        union { uint32_t u[4]; bf16x8 v; } cv;
        cv.u[0] = Aw; cv.u[1] = Bw2; cv.u[2] = Cw; cv.u[3] = Dw;
        pf[ks] = cv.v;
      }

      __builtin_amdgcn_s_setprio(1);
#pragma unroll
      for (int cb = 0; cb < 2; ++cb)
#pragma unroll
        for (int ks = 0; ks < 4; ++ks)
          acc[qb][cb] = mfma32_bf16(vf[cb][ks], pf[ks], acc[qb][cb]);
      __builtin_amdgcn_s_setprio(0);
    }

    // E: all waves done reading buffer p before next iter overwrites sibling
    __builtin_amdgcn_sched_barrier(0);
    __builtin_amdgcn_s_barrier();
    asm volatile("" ::: "memory");
  }

#pragma unroll
  for (int qb = 0; qb < 2; ++qb) {
    const float l = l_run[qb] + __shfl_xor(l_run[qb], 32);
    const float inv = 1.f / l;
    const size_t rowb = ((size_t)(b * T_ + (qw0 + qb) * 32 + q5)) << 9;
#pragma unroll
    for (int cb = 0; cb < 2; ++cb)
#pragma unroll
      for (int m = 0; m < 4; ++m) {
        u32x2 o;
        o.x = cvtpk_bf16(acc[qb][cb][4 * m] * inv, acc[qb][cb][4 * m + 1] * inv);
        o.y = cvtpk_bf16(acc[qb][cb][4 * m + 2] * inv, acc[qb][cb][4 * m + 3] * inv);
        *(u32x2*)&aT[rowb + h * 64 + cb * 32 + 8 * m + 4 * hi] = o;
      }
  }
}

extern "C" void kernel_launch(void* const* d_in, const int* in_sizes, int n_in,
                              void* d_out, int out_size, void* d_ws, size_t ws_size,
                              hipStream_t stream) {
  (void)in_sizes; (void)n_in; (void)out_size; (void)ws_size;
  const float* x      = (const float*)d_in[0];
  const float* gn_w   = (const float*)d_in[1];
  const float* gn_b   = (const float*)d_in[2];
  const float* qkv_w  = (const float*)d_in[3];
  const float* qkv_b  = (const float*)d_in[4];
  const float* proj_w = (const float*)d_in[5];
  const float* proj_b = (const float*)d_in[6];
  float* out = (float*)d_out;

  char* ws = (char*)d_ws;
  unsigned short* wq  = (unsigned short*)(ws);             // 1536x512 bf16
  unsigned short* wp  = (unsigned short*)(ws + 1572864);   // 512x512 bf16
  unsigned short* xnT = (unsigned short*)(ws + 2097152);   // [16][1024][512] bf16 (also aT)
  unsigned short* Qf  = (unsigned short*)(ws + 18874368);  // frag-ordered, 16MB
  unsigned short* Kf  = (unsigned short*)(ws + 35651584);  // frag-ordered, 16MB
  unsigned short* Vf  = (unsigned short*)(ws + 52428800);  // frag-ordered, 16MB

  convert_w_kernel<<<1024, 256, 0, stream>>>(qkv_w, proj_w, wq, wp);
  groupnorm_kernel<<<512, 256, 0, stream>>>(x, gn_w, gn_b, xnT);
  gemm_nt_kernel<0><<<dim3(12, 8, 16), 256, 0, stream>>>(xnT, wq, qkv_b, Qf, Kf, Vf,
                                                         nullptr, nullptr);
  attn_kernel<<<512, 256, 0, stream>>>(Qf, Kf, Vf, xnT /*aT alias*/);
  gemm_nt_kernel<1><<<dim3(4, 8, 16), 256, 0, stream>>>(xnT, wp, proj_b, nullptr,
                                                        nullptr, nullptr, x, out);
}

// Round 20
// 114.914 us; speedup vs baseline: 1.0990x; 1.0264x over previous
//
#include <hip/hip_runtime.h>
#include <hip/hip_bf16.h>
#include <stdint.h>

#define B_ 16
#define C_ 512
#define T_ 1024
#define NH_ 8

typedef __attribute__((ext_vector_type(8))) short bf16x8;
typedef __attribute__((ext_vector_type(4))) float f32x4;
typedef __attribute__((ext_vector_type(16))) float f32x16;
typedef __attribute__((ext_vector_type(4))) unsigned short us4;
typedef __attribute__((ext_vector_type(4))) uint32_t u32x4;
typedef __attribute__((ext_vector_type(2))) uint32_t u32x2;

__device__ __forceinline__ unsigned short f2bf(float f) {
  union { float f; uint32_t u; } v; v.f = f;
  uint32_t r = v.u + 0x7FFFu + ((v.u >> 16) & 1u);
  return (unsigned short)(r >> 16);
}

__device__ __forceinline__ uint32_t cvtpk_bf16(float lo, float hi) {
  uint32_t r;
  asm("v_cvt_pk_bf16_f32 %0, %1, %2" : "=v"(r) : "v"(lo), "v"(hi));
  return r;
}

__device__ __forceinline__ f32x4 mfma_bf16(bf16x8 a, bf16x8 b, f32x4 c) {
  asm("v_mfma_f32_16x16x32_bf16 %0, %1, %2, %0" : "+v"(c) : "v"(a), "v"(b));
  return c;
}

__device__ __forceinline__ f32x16 mfma32_bf16(bf16x8 a, bf16x8 b, f32x16 c) {
  asm("v_mfma_f32_32x32x16_bf16 %0, %1, %2, %0" : "+v"(c) : "v"(a), "v"(b));
  return c;
}

// (a,b) -> a' = {a.lo32, b.lo32}, b' = {a.hi32, b.hi32}
__device__ __forceinline__ void swap32(uint32_t& a, uint32_t& b) {
  asm("v_permlane32_swap_b32 %0, %1" : "+v"(a), "+v"(b));
}

typedef const __attribute__((address_space(1))) uint32_t* gas1_t;
typedef __attribute__((address_space(3))) uint32_t* las3_t;

// async global->LDS, 16B per lane; lds dest = wave-uniform base + lane*16
__device__ __forceinline__ void async16(const void* g, void* lds) {
  __builtin_amdgcn_global_load_lds((gas1_t)(uintptr_t)g,
                                   (las3_t)(uint32_t)(uintptr_t)lds, 16, 0, 0);
}

// q pre-scale folded into QKV epilogue: scale^2 * log2(e)
#define SCLF 0.18033688011112044f

// ---------------- GroupNorm (blocks 0..511) + weight conversion (512..1535) ----------------
// Fused: the 4MB fp32->bf16 weight conversion rides along with the BW-bound
// groupnorm instead of costing its own dispatch. Disjoint block ranges, no
// shared state.
__global__ __launch_bounds__(256) void groupnorm_kernel(
    const float* __restrict__ x, const float* __restrict__ gn_w,
    const float* __restrict__ gn_b, unsigned short* __restrict__ xnT,
    const float* __restrict__ qkv_w, const float* __restrict__ proj_w,
    unsigned short* __restrict__ wq, unsigned short* __restrict__ wp) {
  if (blockIdx.x >= 512) {
    // ---- weight conversion fp32 -> bf16 (1024 blocks) ----
    int i = (blockIdx.x - 512) * 256 + threadIdx.x;  // float4 index, 262144 total
    const float4* src;
    unsigned short* dst;
    int rel = i;
    if (i < 196608) { src = (const float4*)qkv_w; dst = wq; }
    else            { src = (const float4*)proj_w; dst = wp; rel = i - 196608; }
    float4 v = src[rel];
    us4 o;
    o.x = f2bf(v.x); o.y = f2bf(v.y); o.z = f2bf(v.z); o.w = f2bf(v.w);
    *(us4*)&dst[(size_t)rel * 4] = o;
    return;
  }

  const int blk = blockIdx.x;   // b*32+g
  const int b = blk >> 5, g = blk & 31;
  const int tid = threadIdx.x;
  const float4* x4 = (const float4*)(x + (((size_t)(b * C_ + g * 16)) << 10));

  float4 v[16];
  float s1 = 0.f, s2 = 0.f;
#pragma unroll
  for (int i = 0; i < 16; ++i) {
    v[i] = x4[tid + i * 256];
    s1 += v[i].x + v[i].y + v[i].z + v[i].w;
    s2 += v[i].x * v[i].x + v[i].y * v[i].y + v[i].z * v[i].z + v[i].w * v[i].w;
  }
#pragma unroll
  for (int m = 32; m; m >>= 1) { s1 += __shfl_xor(s1, m); s2 += __shfl_xor(s2, m); }

  __shared__ float r1[4], r2[4], stats[2];
  const int wv = tid >> 6;
  if ((tid & 63) == 0) { r1[wv] = s1; r2[wv] = s2; }
  __syncthreads();
  if (tid == 0) {
    float a = r1[0] + r1[1] + r1[2] + r1[3];
    float q = r2[0] + r2[1] + r2[2] + r2[3];
    float mean = a * (1.f / 16384.f);
    float var = q * (1.f / 16384.f) - mean * mean;
    stats[0] = mean;
    stats[1] = rsqrtf(var + 1e-5f);
  }
  __syncthreads();
  const float mean = stats[0], rsig = stats[1];

  float wc[16], bc[16];
#pragma unroll
  for (int c = 0; c < 16; ++c) {
    const float w0 = gn_w[g * 16 + c] * rsig;
    wc[c] = w0;
    bc[c] = gn_b[g * 16 + c] - mean * w0;
  }
#pragma unroll
  for (int r = 0; r < 4; ++r) {
    uint32_t o[8];
#pragma unroll
    for (int c2 = 0; c2 < 8; ++c2) {
      const float a = ((const float*)&v[2 * c2])[r] * wc[2 * c2] + bc[2 * c2];
      const float q = ((const float*)&v[2 * c2 + 1])[r] * wc[2 * c2 + 1] + bc[2 * c2 + 1];
      o[c2] = cvtpk_bf16(a, q);
    }
    unsigned short* dst = &xnT[(((size_t)(b * T_ + tid * 4 + r)) << 9) + g * 16];
    u32x4 lo; lo.x = o[0]; lo.y = o[1]; lo.z = o[2]; lo.w = o[3];
    u32x4 hi; hi.x = o[4]; hi.y = o[5]; hi.z = o[6]; hi.w = o[7];
    *(u32x4*)dst = lo;
    *(u32x4*)(dst + 8) = hi;
  }
}

// ---------------- GEMM: D[m=t][n=o] = sum_k A[t][k] * Bw[o][k] ----------------
// MODE 0: epilogue routes through LDS -> coalesced 1KB stores into 32x32-MFMA
//   fragment-ordered buffers:
//   Qf/Kf (B/A-frag): [bh][qb32(32)][ks(4)][lane(64)][8]
//   Vf (A-frag, V^T): [bh][kt64(16)][ks(4)][cb(2)][lane(64)][8]
//   MODE 0 also applies a bijective XCD swizzle (1536 = 8*192) so each XCD
//   works on 2 contiguous batches (A+B working set ~3.5MB <= 4MB L2).
// MODE 1: proj epilogue (fp32 out = acc + bias + residual)
template <int MODE>
__global__ __launch_bounds__(256) void gemm_nt_kernel(
    const unsigned short* __restrict__ A, const unsigned short* __restrict__ Bw,
    const float* __restrict__ bias, unsigned short* __restrict__ qfb,
    unsigned short* __restrict__ kfb, unsigned short* __restrict__ vfb,
    const float* __restrict__ xres, float* __restrict__ out) {
  int bx = blockIdx.x, by = blockIdx.y, bz = blockIdx.z;
  if constexpr (MODE == 0) {
    const int lin = bx + 12 * (by + 8 * bz);       // [0,1536)
    const int swz = (lin & 7) * 192 + (lin >> 3);  // bijective permutation
    bx = swz % 12; by = (swz / 12) & 7; bz = swz / 96;
  }
  const int b = bz;
  const int m0 = by * 128;
  const int n0 = bx * 128;
  const int tid = threadIdx.x;
  const int w = tid >> 6, ln = tid & 63;
  const int r15 = ln & 15, r4 = ln >> 4;

  __shared__ __attribute__((aligned(16))) char smem[40960];
  unsigned short* As = (unsigned short*)smem;            // staging 16KB
  unsigned short* Bs = (unsigned short*)(smem + 16384);  // staging 16KB

  const unsigned short* Ab = A + (((size_t)(b * T_ + m0)) << 9);
  const unsigned short* Bb = Bw + ((size_t)n0 << 9);

  f32x4 acc[4][4] = {};
  const int wm = (w >> 1) << 6, wn = (w & 1) << 6;

  for (int kt = 0; kt < 8; ++kt) {
    const int k0 = kt << 6;
    __syncthreads();
#pragma unroll
    for (int j = 0; j < 4; ++j) {
      const int slot = (j << 6) + ln;
      const int row = slot >> 3;
      const int chg = (slot & 7) ^ (row & 7);   // pre-swizzled source chunk
      async16(Ab + (((size_t)(w * 32 + row)) << 9) + k0 + chg * 8,
              (char*)As + w * 4096 + j * 1024);
      async16(Bb + (((size_t)(w * 32 + row)) << 9) + k0 + chg * 8,
              (char*)Bs + w * 4096 + j * 1024);
    }
    __syncthreads();
#pragma unroll
    for (int kk = 0; kk < 2; ++kk) {
      bf16x8 af[4], bfr[4];
#pragma unroll
      for (int i = 0; i < 4; ++i) {
        const int ra = wm + i * 16 + r15;
        const int ch = r4 + kk * 4;
        af[i] = *(const bf16x8*)((const char*)As + ra * 128 + ((ch ^ (ra & 7)) << 4));
        const int rb = wn + i * 16 + r15;
        bfr[i] = *(const bf16x8*)((const char*)Bs + rb * 128 + ((ch ^ (rb & 7)) << 4));
      }
#pragma unroll
      for (int i = 0; i < 4; ++i)
#pragma unroll
        for (int j = 0; j < 4; ++j)
          acc[i][j] = mfma_bf16(af[i], bfr[j], acc[i][j]);
    }
  }

  if constexpr (MODE == 0) {
    __syncthreads();  // staging reads done; LDS reused by epilogue
    const int seg = w & 1;               // this wave's 64-col segment
    const int typ3 = (n0 >> 7) % 3;      // 0:{q,k} 1:{v,q} 2:{k,v}
    int st;                              // 0=q 1=k 2=v
    if (typ3 == 0) st = seg;
    else if (typ3 == 1) st = seg ? 0 : 2;
    else st = seg ? 2 : 1;
    const int hseg = (n0 + seg * 64) / 192;
    char* segp = smem + seg * 20480;
    const int q5 = ln & 31, hi = ln >> 5;

    if (st < 2) {
      // [t(128)][c(80 padded)] bf16
      unsigned short* qkL = (unsigned short*)segp;
      const float scl = (st == 0) ? SCLF : 1.f;
#pragma unroll
      for (int j = 0; j < 4; ++j) {
        const int c = j * 16 + r15;
        const float bsv = bias[n0 + seg * 64 + c];
#pragma unroll
        for (int i = 0; i < 4; ++i) {
          const int t0 = wm + i * 16 + r4 * 4;
#pragma unroll
          for (int r = 0; r < 4; ++r)
            qkL[(t0 + r) * 80 + c] = f2bf((acc[i][j][r] + bsv) * scl);
        }
      }
      __syncthreads();
      unsigned short* dst = (st == 0) ? qfb : kfb;
      const size_t hb = ((size_t)(b * NH_ + hseg)) << 16;
#pragma unroll
      for (int u = 0; u < 8; ++u) {
        const int qbl = (w >> 1) * 2 + (u >> 2);   // local 32-row block
        const int ks = u & 3;
        bf16x8 val = *(const bf16x8*)&qkL[(qbl * 32 + q5) * 80 + ks * 16 + hi * 8];
        *(bf16x8*)&dst[hb + ((((m0 >> 5) + qbl) * 4 + ks) * 64 + ln) * 8] = val;
      }
    } else {
      // [ch(64)][t(144 padded)] bf16 (transposed)
      unsigned short* vL = (unsigned short*)segp;
#pragma unroll
      for (int j = 0; j < 4; ++j) {
        const int c = j * 16 + r15;
        const float bsv = bias[n0 + seg * 64 + c];
#pragma unroll
        for (int i = 0; i < 4; ++i) {
          const int t0 = wm + i * 16 + r4 * 4;
          u32x2 pk;
          pk.x = cvtpk_bf16(acc[i][j][0] + bsv, acc[i][j][1] + bsv);
          pk.y = cvtpk_bf16(acc[i][j][2] + bsv, acc[i][j][3] + bsv);
          *(u32x2*)&vL[c * 144 + t0] = pk;
        }
      }
      __syncthreads();
      const size_t hb = ((size_t)(b * NH_ + hseg)) << 16;
      const int ktl = w >> 1;                      // local 64-key tile
#pragma unroll
      for (int u = 0; u < 8; ++u) {
        const int ks = u >> 1, cb = u & 1;
        bf16x8 val = *(const bf16x8*)&vL[(cb * 32 + q5) * 144 +
                                         ktl * 64 + ks * 16 + hi * 8];
        *(bf16x8*)&vfb[hb + ((((m0 >> 6) + ktl) * 8 + ks * 2 + cb) * 64 + ln) * 8] = val;
      }
    }
  } else {
#pragma unroll
    for (int i = 0; i < 4; ++i) {
      const int t = m0 + wm + i * 16 + r4 * 4;
#pragma unroll
      for (int j = 0; j < 4; ++j) {
        const int o = n0 + wn + j * 16 + r15;
        const float bsv = bias[o];
        const size_t base = (((size_t)(b * C_ + o)) << 10) + t;
        const float4 xr = *(const float4*)&xres[base];
        float4 ov;
        ov.x = acc[i][j][0] + bsv + xr.x;
        ov.y = acc[i][j][1] + bsv + xr.y;
        ov.z = acc[i][j][2] + bsv + xr.z;
        ov.w = acc[i][j][3] + bsv + xr.w;
        *(float4*)&out[base] = ov;
      }
    }
  }
}

// ---------------- flash attention v10: 64 q/wave + LDS K/V pipeline ----------------
// (exact R14/R19 passing kernel) kf/vf come from LDS, staged once per block via
// global_load_lds (tile = contiguous 8KB in the fragment layout -> linear
// memcpy), double-buffered with the proven counted-vmcnt + raw-s_barrier
// schedule. All 4 waves share K/V.
__global__ __launch_bounds__(256) void attn_kernel(
    const unsigned short* __restrict__ Qf, const unsigned short* __restrict__ Kf,
    const unsigned short* __restrict__ Vf, unsigned short* __restrict__ aT) {
  const int lin = blockIdx.x;                   // 512 blocks
  const int bh = (lin & 7) * 16 + (lin >> 5);   // same bh -> same lin%8 -> same XCD
  const int qt = (lin >> 3) & 3;                // 4 x 256-query tiles
  const int b = bh >> 3, h = bh & 7;
  const int tid = threadIdx.x;
  const int w = tid >> 6, ln = tid & 63;
  const int q5 = ln & 31, hi = ln >> 5;

  __shared__ __attribute__((aligned(16))) unsigned short Ks[2][4096];  // 8KB/tile
  __shared__ __attribute__((aligned(16))) unsigned short Vs[2][4096];

  const unsigned short* qb_ = Qf + ((size_t)bh << 16);
  const unsigned short* kb = Kf + ((size_t)bh << 16);
  const unsigned short* vb = Vf + ((size_t)bh << 16);
  const int qw0 = qt * 8 + w * 2;   // first of this wave's two 32-q blocks

  // staging role: waves 0,1 -> K halves; waves 2,3 -> V halves (4KB each)
  const unsigned short* sgb = (w < 2) ? kb : vb;
  const int shalf = (w & 1) * 2048;

  // prologue: stage tile 0 (4 async16/wave), then Q -> registers
#pragma unroll
  for (int j = 0; j < 4; ++j)
    async16(sgb + shalf + j * 512 + ln * 8,
            (char*)(w < 2 ? Ks[0] : Vs[0]) + (w & 1) * 4096 + j * 1024);

  bf16x8 qf[2][4];
#pragma unroll
  for (int qb = 0; qb < 2; ++qb)
#pragma unroll
    for (int ks = 0; ks < 4; ++ks)
      qf[qb][ks] = *(const bf16x8*)(qb_ + ((((qw0 + qb) * 4 + ks) * 64 + ln) << 3));

  float l_run[2] = {0.f, 0.f};
  f32x16 acc[2][2] = {};   // [qb][cb]

  for (int t = 0; t < 16; ++t) {
    const int p = t & 1;
    // A: stage next tile into the other buffer (tile = 4096 shorts, linear)
    if (t < 15) {
      const int nt = (t + 1) * 4096;
#pragma unroll
      for (int j = 0; j < 4; ++j)
        async16(sgb + nt + shalf + j * 512 + ln * 8,
                (char*)(w < 2 ? Ks[p ^ 1] : Vs[p ^ 1]) + (w & 1) * 4096 + j * 1024);
      __builtin_amdgcn_sched_barrier(0);
      asm volatile("s_waitcnt vmcnt(4)" ::: "memory");
    } else {
      __builtin_amdgcn_sched_barrier(0);
      asm volatile("s_waitcnt vmcnt(0)" ::: "memory");
    }
    // B: tile t staged everywhere; no reader left on buffer p^1
    __builtin_amdgcn_s_barrier();
    asm volatile("" ::: "memory");
    __builtin_amdgcn_sched_barrier(0);

    // K/V fragments from LDS (same indexing as the old global reads)
    bf16x8 kf[2][4], vf[2][4];
#pragma unroll
    for (int k2 = 0; k2 < 2; ++k2)
#pragma unroll
      for (int ks = 0; ks < 4; ++ks)
        kf[k2][ks] = *(const bf16x8*)((const char*)Ks[p] +
                                      (((k2 * 4 + ks) << 10) + ln * 16));
#pragma unroll
    for (int cb = 0; cb < 2; ++cb)
#pragma unroll
      for (int ks = 0; ks < 4; ++ks)
        vf[cb][ks] = *(const bf16x8*)((const char*)Vs[p] +
                                      (((ks * 2 + cb) << 10) + ln * 16));

    // D1: S^T = K.Q for both q-blocks
    f32x16 s[2][2] = {};   // [qb][k2]
    __builtin_amdgcn_s_setprio(1);
#pragma unroll
    for (int qb = 0; qb < 2; ++qb)
#pragma unroll
      for (int k2 = 0; k2 < 2; ++k2)
#pragma unroll
        for (int ks = 0; ks < 4; ++ks)
          s[qb][k2] = mfma32_bf16(kf[k2][ks], qf[qb][ks], s[qb][k2]);
    __builtin_amdgcn_s_setprio(0);

    // D2+D3 per q-block: exp, tree-sum, pack/permlane, PV
#pragma unroll
    for (int qb = 0; qb < 2; ++qb) {
      float pe[32];
#pragma unroll
      for (int u = 0; u < 16; ++u)
        pe[u] = __builtin_amdgcn_exp2f(s[qb][0][u]);
#pragma unroll
      for (int u = 0; u < 16; ++u)
        pe[16 + u] = __builtin_amdgcn_exp2f(s[qb][1][u]);

      float sm[16];
#pragma unroll
      for (int m = 0; m < 16; ++m) sm[m] = pe[2 * m] + pe[2 * m + 1];
#pragma unroll
      for (int d = 8; d; d >>= 1)
#pragma unroll
        for (int m = 0; m < 8; ++m)
          if (m < d) sm[m] += sm[m + d];
      l_run[qb] += sm[0];   // cross-half shfl deferred to epilogue

      bf16x8 pf[4];
#pragma unroll
      for (int ks = 0; ks < 4; ++ks) {
        const float* ps = pe + ks * 8;
        uint32_t Aw = cvtpk_bf16(ps[0], ps[1]);
        uint32_t Bw2 = cvtpk_bf16(ps[2], ps[3]);
        uint32_t Cw = cvtpk_bf16(ps[4], ps[5]);
        uint32_t Dw = cvtpk_bf16(ps[6], ps[7]);
        swap32(Aw, Cw);    // Aw -> W0, Cw -> W2
        swap32(Bw2, Dw);   // Bw2 -> W1, Dw -> W3
        union { uint32_t u[4]; bf16x8 v; } cv;
        cv.u[0] = Aw; cv.u[1] = Bw2; cv.u[2] = Cw; cv.u[3] = Dw;
        pf[ks] = cv.v;
      }

      __builtin_amdgcn_s_setprio(1);
#pragma unroll
      for (int cb = 0; cb < 2; ++cb)
#pragma unroll
        for (int ks = 0; ks < 4; ++ks)
          acc[qb][cb] = mfma32_bf16(vf[cb][ks], pf[ks], acc[qb][cb]);
      __builtin_amdgcn_s_setprio(0);
    }

    // E: all waves done reading buffer p before next iter overwrites sibling
    __builtin_amdgcn_sched_barrier(0);
    __builtin_amdgcn_s_barrier();
    asm volatile("" ::: "memory");
  }

#pragma unroll
  for (int qb = 0; qb < 2; ++qb) {
    const float l = l_run[qb] + __shfl_xor(l_run[qb], 32);
    const float inv = 1.f / l;
    const size_t rowb = ((size_t)(b * T_ + (qw0 + qb) * 32 + q5)) << 9;
#pragma unroll
    for (int cb = 0; cb < 2; ++cb)
#pragma unroll
      for (int m = 0; m < 4; ++m) {
        u32x2 o;
        o.x = cvtpk_bf16(acc[qb][cb][4 * m] * inv, acc[qb][cb][4 * m + 1] * inv);
        o.y = cvtpk_bf16(acc[qb][cb][4 * m + 2] * inv, acc[qb][cb][4 * m + 3] * inv);
        *(u32x2*)&aT[rowb + h * 64 + cb * 32 + 8 * m + 4 * hi] = o;
      }
  }
}

extern "C" void kernel_launch(void* const* d_in, const int* in_sizes, int n_in,
                              void* d_out, int out_size, void* d_ws, size_t ws_size,
                              hipStream_t stream) {
  (void)in_sizes; (void)n_in; (void)out_size; (void)ws_size;
  const float* x      = (const float*)d_in[0];
  const float* gn_w   = (const float*)d_in[1];
  const float* gn_b   = (const float*)d_in[2];
  const float* qkv_w  = (const float*)d_in[3];
  const float* qkv_b  = (const float*)d_in[4];
  const float* proj_w = (const float*)d_in[5];
  const float* proj_b = (const float*)d_in[6];
  float* out = (float*)d_out;

  char* ws = (char*)d_ws;
  unsigned short* wq  = (unsigned short*)(ws);             // 1536x512 bf16
  unsigned short* wp  = (unsigned short*)(ws + 1572864);   // 512x512 bf16
  unsigned short* xnT = (unsigned short*)(ws + 2097152);   // [16][1024][512] bf16 (also aT)
  unsigned short* Qf  = (unsigned short*)(ws + 18874368);  // frag-ordered, 16MB
  unsigned short* Kf  = (unsigned short*)(ws + 35651584);  // frag-ordered, 16MB
  unsigned short* Vf  = (unsigned short*)(ws + 52428800);  // frag-ordered, 16MB

  groupnorm_kernel<<<1536, 256, 0, stream>>>(x, gn_w, gn_b, xnT,
                                             qkv_w, proj_w, wq, wp);
  gemm_nt_kernel<0><<<dim3(12, 8, 16), 256, 0, stream>>>(xnT, wq, qkv_b, Qf, Kf, Vf,
                                                         nullptr, nullptr);
  attn_kernel<<<512, 256, 0, stream>>>(Qf, Kf, Vf, xnT /*aT alias*/);
  gemm_nt_kernel<1><<<dim3(4, 8, 16), 256, 0, stream>>>(xnT, wp, proj_b, nullptr,
                                                        nullptr, nullptr, x, out);
}